// Round 3
// baseline (478.425 us; speedup 1.0000x reference)
//
#include <hip/hip_runtime.h>
#include <stdint.h>

typedef __bf16 bf16x8 __attribute__((ext_vector_type(8)));
typedef float f32x4 __attribute__((ext_vector_type(4)));
typedef unsigned short ushort_t;

#define N_OUT 11008
#define K_DIM 4096
#define M_DIM 512
#define BM 256
#define BN 64
#define BK 64
#define KHALF 2048
#define NT 32            /* KHALF / BK */
#define LDB 72           /* padded lds_b row, ushorts */
#define BUF (64 * LDB)   /* one B buffer, ushorts */

__constant__ float c_nf4[16] = {
    -1.0f, -0.6961928009986877f, -0.5250730514526367f, -0.39491748809814453f,
    -0.28444138169288635f, -0.18477343022823334f, -0.09105003625154495f, 0.0f,
    0.07958029955625534f, 0.16093020141124725f, 0.24611230194568634f,
    0.33791524171829224f, 0.44070982933044434f, 0.5626170039176941f,
    0.7229568362236023f, 1.0f};

__device__ __forceinline__ uint32_t pkbf(float lo, float hi) {
  uint32_t ul = __builtin_bit_cast(uint32_t, lo);
  uint32_t uh = __builtin_bit_cast(uint32_t, hi);
  return ((ul + 0x8000u) >> 16) | ((uh + 0x8000u) & 0xffff0000u);
}

__device__ __forceinline__ bf16x8 ldfrag(const ushort_t* p) {
  uint4 r = *reinterpret_cast<const uint4*>(p);
  return __builtin_bit_cast(bf16x8, r);
}

__device__ __forceinline__ bf16x8 asfrag(uint4 r) {
  return __builtin_bit_cast(bf16x8, r);
}

__device__ __forceinline__ uint32_t dq2(int a, int b, float s, const float2* lut) {
  float2 l = lut[a | (b << 4)];
  return pkbf(l.x * s, l.y * s);
}

// =============== fused prep: cvt | x@A | B^T | bias-init =====================
// grid: [0,1024) cvt, [1024,1536) xa, [1536,1579) bt, [1579,7083) bias-init
__global__ void k_prep(const float* __restrict__ x, const float* __restrict__ lA,
                       const float* __restrict__ lB, const float* __restrict__ bias,
                       ushort_t* __restrict__ xbf, ushort_t* __restrict__ xap,
                       ushort_t* __restrict__ btp, float* __restrict__ out) {
  __shared__ float red[16][17];  // xa branch only (1.1 KB, harmless elsewhere)
  const int b = blockIdx.x, t = threadIdx.x;
  if (b < 1024) {
    // x fp32 -> bf16, row-major (no swizzle: A path is register-direct now)
    int oc = b * 256 + t;  // 16B chunk id (8 bf16), 262144 total
    const float4* s4 = reinterpret_cast<const float4*>(x) + (size_t)oc * 2;
    float4 v0 = s4[0], v1 = s4[1];
    uint4 o;
    o.x = pkbf(v0.x, v0.y);
    o.y = pkbf(v0.z, v0.w);
    o.z = pkbf(v1.x, v1.y);
    o.w = pkbf(v1.z, v1.w);
    ((uint4*)xbf)[oc] = o;
  } else if (b < 1536) {
    // xa = 2*(x @ lora_A) for row m, padded [512,32] bf16
    int m = b - 1024;
    int r = t & 15, part = t >> 4;
    const float* xr = x + (size_t)m * K_DIM + part * 256;
    const float* ar = lA + (size_t)(part * 256) * 16 + r;
    float acc = 0.f;
#pragma unroll 8
    for (int k = 0; k < 256; ++k) acc += xr[k] * ar[(size_t)k * 16];
    red[part][r] = acc;
    __syncthreads();
    if (t < 32) {
      float v = 0.f;
      if (t < 16) {
        for (int p = 0; p < 16; ++p) v += red[p][t];
        v *= 2.0f;  // SCALING
      }
      uint32_t u = __builtin_bit_cast(uint32_t, v);
      xap[(size_t)m * 32 + t] = (ushort_t)((u + 0x8000u) >> 16);
    }
  } else if (b < 1579) {
    // Bt = lora_B^T, padded [11008,32] bf16
    int o = (b - 1536) * 256 + t;
    uint32_t p[8];
#pragma unroll
    for (int j = 0; j < 8; ++j)
      p[j] = pkbf(lB[(size_t)(2 * j) * N_OUT + o], lB[(size_t)(2 * j + 1) * N_OUT + o]);
    uint4* dst = reinterpret_cast<uint4*>(btp + (size_t)o * 32);
    dst[0] = make_uint4(p[0], p[1], p[2], p[3]);
    dst[1] = make_uint4(p[4], p[5], p[6], p[7]);
    dst[2] = make_uint4(0u, 0u, 0u, 0u);
    dst[3] = make_uint4(0u, 0u, 0u, 0u);
  } else {
    // out = broadcast bias (split-K blocks atomically add on top)
    int i = (b - 1579) * 256 + t;  // float4 id, 1,409,024 total
    int col4 = i % 2752;           // 11008/4
    ((float4*)out)[i] = ((const float4*)bias)[col4];
  }
}

// =============== main fused GEMM ============================================
// BM=256 x BN=64, BK=64, splitK=2. 4 waves, wave w owns rows [w*64,w*64+64).
// A: register-direct global loads (prefetch depth 1) — no LDS, no vmcnt drain
//    at barriers. B: idx register prefetch depth 2 -> pair-LUT dequant ->
//    triple-buffered LDS -> ONE barrier per tile. LoRA tail register-direct.
__launch_bounds__(256, 3)
__global__ void k_main(const ushort_t* __restrict__ xbf, const int* __restrict__ wi,
                       const float* __restrict__ sc, const ushort_t* __restrict__ xap,
                       const ushort_t* __restrict__ btp, float* __restrict__ out) {
  __shared__ __align__(16) ushort_t lds_b[3 * BUF];  // 27.6 KB
  __shared__ float2 lutp[256];                       // pair LUT, 2 KB

  const int t = threadIdx.x;
  const int lane = t & 63;
  const int w = t >> 6;
  const int q = lane >> 4;
  const int m0 = blockIdx.x * BM;   // m-blocks fastest: index-sharing neighbors
  const int o0 = blockIdx.y * BN;
  const int kh = blockIdx.z;
  const int k0 = kh * KHALF;

  lutp[t] = make_float2(c_nf4[t & 15], c_nf4[t >> 4]);

  // B idx staging: thread -> (row=t>>2, 16 ints at (t&3)*16)
  const int brow = t >> 2, bq = t & 3;
  const int* gb = wi + (size_t)(o0 + brow) * K_DIM + k0 + bq * 16;
  const float* gs = sc + (size_t)(o0 + brow) * 64 + kh * 32;  // 1 scale/row/tile
  const int lbo = brow * LDB + bq * 16;  // ushort offset within a buffer

  // A register-direct base: row = m0 + w*64 + mi*16 + (lane&15), 16B at q*8
  const ushort_t* gA =
      xbf + (size_t)(m0 + w * 64 + (lane & 15)) * K_DIM + k0 + q * 8;

  f32x4 acc[4][4];
#pragma unroll
  for (int mi = 0; mi < 4; ++mi)
#pragma unroll
    for (int ni = 0; ni < 4; ++ni) acc[mi][ni] = (f32x4){0.f, 0.f, 0.f, 0.f};

  // ---- prologue: idx tiles 0,1; A tile 0; LUT barrier; dequant tile 0
  int4 bi[2][4];
  float bs[2];
  uint4 a_reg[4][2];
#pragma unroll
  for (int j = 0; j < 4; ++j) bi[0][j] = reinterpret_cast<const int4*>(gb)[j];
  bs[0] = gs[0];
#pragma unroll
  for (int j = 0; j < 4; ++j) bi[1][j] = reinterpret_cast<const int4*>(gb + 64)[j];
  bs[1] = gs[1];
#pragma unroll
  for (int mi = 0; mi < 4; ++mi)
#pragma unroll
    for (int kc = 0; kc < 2; ++kc)
      a_reg[mi][kc] = *reinterpret_cast<const uint4*>(gA + (size_t)mi * 16 * K_DIM + kc * 32);

  __syncthreads();  // lutp visible

  {  // dequant tile 0 -> buffer 0
    ushort_t* lb = lds_b + lbo;
    uint4 w0, w1;
    w0.x = dq2(bi[0][0].x, bi[0][0].y, bs[0], lutp);
    w0.y = dq2(bi[0][0].z, bi[0][0].w, bs[0], lutp);
    w0.z = dq2(bi[0][1].x, bi[0][1].y, bs[0], lutp);
    w0.w = dq2(bi[0][1].z, bi[0][1].w, bs[0], lutp);
    w1.x = dq2(bi[0][2].x, bi[0][2].y, bs[0], lutp);
    w1.y = dq2(bi[0][2].z, bi[0][2].w, bs[0], lutp);
    w1.z = dq2(bi[0][3].x, bi[0][3].y, bs[0], lutp);
    w1.w = dq2(bi[0][3].z, bi[0][3].w, bs[0], lutp);
    *reinterpret_cast<uint4*>(lb) = w0;
    *reinterpret_cast<uint4*>(lb + 8) = w1;
  }
#pragma unroll
  for (int j = 0; j < 4; ++j) bi[0][j] = reinterpret_cast<const int4*>(gb + 128)[j];
  bs[0] = gs[2];  // set0 now holds tile 2

  unsigned off_r = 0, off_w = BUF, off_s = 2 * BUF;

#pragma unroll 2
  for (int kt = 0; kt < NT; ++kt) {
    __syncthreads();  // buf[off_r] (tile kt) visible; slot reuse ≥2 apart
    // B fragments for tile kt
    const ushort_t* bb = lds_b + off_r + (lane & 15) * LDB + q * 8;
    bf16x8 bv0[4], bv1[4];
#pragma unroll
    for (int ni = 0; ni < 4; ++ni) bv0[ni] = ldfrag(bb + ni * 16 * LDB);
#pragma unroll
    for (int ni = 0; ni < 4; ++ni) bv1[ni] = ldfrag(bb + ni * 16 * LDB + 32);
    // dequant tile kt+1 -> buf[off_w] (overlaps with MFMA issue below)
    const int ns = (kt + 1) & 1;  // static after unroll-2
    if (kt + 1 < NT) {
      ushort_t* lb = lds_b + off_w + lbo;
      uint4 w0, w1;
      w0.x = dq2(bi[ns][0].x, bi[ns][0].y, bs[ns], lutp);
      w0.y = dq2(bi[ns][0].z, bi[ns][0].w, bs[ns], lutp);
      w0.z = dq2(bi[ns][1].x, bi[ns][1].y, bs[ns], lutp);
      w0.w = dq2(bi[ns][1].z, bi[ns][1].w, bs[ns], lutp);
      w1.x = dq2(bi[ns][2].x, bi[ns][2].y, bs[ns], lutp);
      w1.y = dq2(bi[ns][2].z, bi[ns][2].w, bs[ns], lutp);
      w1.z = dq2(bi[ns][3].x, bi[ns][3].y, bs[ns], lutp);
      w1.w = dq2(bi[ns][3].z, bi[ns][3].w, bs[ns], lutp);
      *reinterpret_cast<uint4*>(lb) = w0;
      *reinterpret_cast<uint4*>(lb + 8) = w1;
    }
    // 32 MFMAs for tile kt (A in registers)
#pragma unroll
    for (int mi = 0; mi < 4; ++mi)
#pragma unroll
      for (int ni = 0; ni < 4; ++ni)
        acc[mi][ni] = __builtin_amdgcn_mfma_f32_16x16x32_bf16(asfrag(a_reg[mi][0]),
                                                              bv0[ni], acc[mi][ni], 0, 0, 0);
#pragma unroll
    for (int mi = 0; mi < 4; ++mi)
#pragma unroll
      for (int ni = 0; ni < 4; ++ni)
        acc[mi][ni] = __builtin_amdgcn_mfma_f32_16x16x32_bf16(asfrag(a_reg[mi][1]),
                                                              bv1[ni], acc[mi][ni], 0, 0, 0);
    // idx prefetch tile kt+3 (depth 2; loads stay in flight across barriers)
    if (kt + 3 < NT) {
      const int4* gp = reinterpret_cast<const int4*>(gb + (size_t)(kt + 3) * 64);
#pragma unroll
      for (int j = 0; j < 4; ++j) bi[ns][j] = gp[j];
      bs[ns] = gs[kt + 3];
    }
    // A prefetch tile kt+1 (or LoRA tail fragments)
    if (kt + 1 < NT) {
#pragma unroll
      for (int mi = 0; mi < 4; ++mi)
#pragma unroll
        for (int kc = 0; kc < 2; ++kc)
          a_reg[mi][kc] = *reinterpret_cast<const uint4*>(
              gA + (size_t)mi * 16 * K_DIM + (size_t)(kt + 1) * 64 + kc * 32);
    } else if (kh == 1) {
#pragma unroll
      for (int mi = 0; mi < 4; ++mi)
        a_reg[mi][0] = *reinterpret_cast<const uint4*>(
            xap + (size_t)(m0 + w * 64 + mi * 16 + (lane & 15)) * 32 + q * 8);
#pragma unroll
      for (int ni = 0; ni < 4; ++ni)
        a_reg[ni][1] = *reinterpret_cast<const uint4*>(
            btp + (size_t)(o0 + ni * 16 + (lane & 15)) * 32 + q * 8);
    }
    unsigned tmp = off_r;  // rotate triple buffer
    off_r = off_w;
    off_w = off_s;
    off_s = tmp;
  }

  // LoRA K-extension tail (kh==1): register-direct, no LDS, no barrier
  if (kh == 1) {
#pragma unroll
    for (int mi = 0; mi < 4; ++mi)
#pragma unroll
      for (int ni = 0; ni < 4; ++ni)
        acc[mi][ni] = __builtin_amdgcn_mfma_f32_16x16x32_bf16(
            asfrag(a_reg[mi][0]), asfrag(a_reg[ni][1]), acc[mi][ni], 0, 0, 0);
  }

  // epilogue: atomic add onto bias-pre-initialized out
  const int cl = lane & 15, rg = q * 4;
#pragma unroll
  for (int ni = 0; ni < 4; ++ni) {
    int col = o0 + ni * 16 + cl;
#pragma unroll
    for (int mi = 0; mi < 4; ++mi) {
      int row0 = m0 + w * 64 + mi * 16 + rg;
      float* op = out + (size_t)row0 * N_OUT + col;
#pragma unroll
      for (int i = 0; i < 4; ++i) atomicAdd(op + (size_t)i * N_OUT, acc[mi][ni][i]);
    }
  }
}

extern "C" void kernel_launch(void* const* d_in, const int* in_sizes, int n_in,
                              void* d_out, int out_size, void* d_ws, size_t ws_size,
                              hipStream_t stream) {
  const float* x = (const float*)d_in[0];
  const int* wi = (const int*)d_in[1];
  const float* sc = (const float*)d_in[2];
  const float* lA = (const float*)d_in[3];
  const float* lB = (const float*)d_in[4];
  const float* bias = (const float*)d_in[5];
  float* out = (float*)d_out;

  char* wsb = (char*)d_ws;
  ushort_t* xbf = (ushort_t*)wsb;                               // 4 MB
  ushort_t* xap = (ushort_t*)(wsb + (4u << 20));                // 32 KB
  ushort_t* btp = (ushort_t*)(wsb + (4u << 20) + (32u << 10));  // 704 KB

  k_prep<<<7083, 256, 0, stream>>>(x, lA, lB, bias, xbf, xap, btp, out);
  dim3 grid(M_DIM / BM, N_OUT / BN, 2);  // m fastest -> index panel sharing
  k_main<<<grid, 256, 0, stream>>>(xbf, wi, sc, xap, btp, out);
}

// Round 4
// 408.942 us; speedup vs baseline: 1.1699x; 1.1699x over previous
//
#include <hip/hip_runtime.h>
#include <stdint.h>

typedef __bf16 bf16x8 __attribute__((ext_vector_type(8)));
typedef float f32x4 __attribute__((ext_vector_type(4)));
typedef unsigned short ushort_t;

#define N_OUT 11008
#define K_DIM 4096
#define M_DIM 512
#define BM 128
#define BN 64
#define BK 64
#define NT 64            /* K_DIM / BK */
#define LDB 72           /* padded lds_b row, ushorts */
#define BUF (64 * LDB)   /* one B buffer, ushorts */

__constant__ float c_nf4[16] = {
    -1.0f, -0.6961928009986877f, -0.5250730514526367f, -0.39491748809814453f,
    -0.28444138169288635f, -0.18477343022823334f, -0.09105003625154495f, 0.0f,
    0.07958029955625534f, 0.16093020141124725f, 0.24611230194568634f,
    0.33791524171829224f, 0.44070982933044434f, 0.5626170039176941f,
    0.7229568362236023f, 1.0f};

__device__ __forceinline__ uint32_t pkbf(float lo, float hi) {
  uint32_t ul = __builtin_bit_cast(uint32_t, lo);
  uint32_t uh = __builtin_bit_cast(uint32_t, hi);
  return ((ul + 0x8000u) >> 16) | ((uh + 0x8000u) & 0xffff0000u);
}

__device__ __forceinline__ bf16x8 ldfrag(const ushort_t* p) {
  uint4 r = *reinterpret_cast<const uint4*>(p);
  return __builtin_bit_cast(bf16x8, r);
}

__device__ __forceinline__ bf16x8 asfrag(uint4 r) {
  return __builtin_bit_cast(bf16x8, r);
}

__device__ __forceinline__ uint32_t dq2(int a, int b, float s, const float2* lut) {
  float2 l = lut[a | (b << 4)];
  return pkbf(l.x * s, l.y * s);
}

// =============== fused prep: cvt | x@A | B^T ================================
// grid: [0,1024) cvt, [1024,1536) xa, [1536,1579) bt
__global__ void k_prep(const float* __restrict__ x, const float* __restrict__ lA,
                       const float* __restrict__ lB, ushort_t* __restrict__ xbf,
                       ushort_t* __restrict__ xap, ushort_t* __restrict__ btp) {
  __shared__ float red[16][17];  // xa branch only
  const int b = blockIdx.x, t = threadIdx.x;
  if (b < 1024) {
    // x fp32 -> bf16 row-major
    int oc = b * 256 + t;  // 16B chunk id (8 bf16), 262144 total
    const float4* s4 = reinterpret_cast<const float4*>(x) + (size_t)oc * 2;
    float4 v0 = s4[0], v1 = s4[1];
    uint4 o;
    o.x = pkbf(v0.x, v0.y);
    o.y = pkbf(v0.z, v0.w);
    o.z = pkbf(v1.x, v1.y);
    o.w = pkbf(v1.z, v1.w);
    ((uint4*)xbf)[oc] = o;
  } else if (b < 1536) {
    // xa = 2*(x @ lora_A) for row m, padded [512,32] bf16
    int m = b - 1024;
    int r = t & 15, part = t >> 4;
    const float* xr = x + (size_t)m * K_DIM + part * 256;
    const float* ar = lA + (size_t)(part * 256) * 16 + r;
    float acc = 0.f;
#pragma unroll 8
    for (int k = 0; k < 256; ++k) acc += xr[k] * ar[(size_t)k * 16];
    red[part][r] = acc;
    __syncthreads();
    if (t < 32) {
      float v = 0.f;
      if (t < 16) {
        for (int p = 0; p < 16; ++p) v += red[p][t];
        v *= 2.0f;  // SCALING
      }
      uint32_t u = __builtin_bit_cast(uint32_t, v);
      xap[(size_t)m * 32 + t] = (ushort_t)((u + 0x8000u) >> 16);
    }
  } else {
    // Bt = lora_B^T, padded [11008,32] bf16
    int o = (b - 1536) * 256 + t;
    uint32_t p[8];
#pragma unroll
    for (int j = 0; j < 8; ++j)
      p[j] = pkbf(lB[(size_t)(2 * j) * N_OUT + o], lB[(size_t)(2 * j + 1) * N_OUT + o]);
    uint4* dst = reinterpret_cast<uint4*>(btp + (size_t)o * 32);
    dst[0] = make_uint4(p[0], p[1], p[2], p[3]);
    dst[1] = make_uint4(p[4], p[5], p[6], p[7]);
    dst[2] = make_uint4(0u, 0u, 0u, 0u);
    dst[3] = make_uint4(0u, 0u, 0u, 0u);
  }
}

// =============== main fused GEMM ============================================
// BM=128 x BN=64, BK=64, full K (no split-K, no atomics). 688 blocks.
// 4 waves; wave w owns rows [w*32, w*32+32): acc[2][4].
// A: register-direct global loads, prefetch depth 1 (no LDS -> no vmcnt drain
//    at barriers). B: idx prefetch depth 2 -> pair-LUT dequant ->
//    triple-buffered LDS -> ONE barrier per tile. LoRA K-ext tail in registers.
// Epilogue: plain stores + bias.
__launch_bounds__(256, 3)
__global__ void k_main(const ushort_t* __restrict__ xbf, const int* __restrict__ wi,
                       const float* __restrict__ sc, const ushort_t* __restrict__ xap,
                       const ushort_t* __restrict__ btp, const float* __restrict__ bias,
                       float* __restrict__ out) {
  __shared__ __align__(16) ushort_t lds_b[3 * BUF];  // 27.6 KB
  __shared__ float2 lutp[256];                       // pair LUT, 2 KB

  const int t = threadIdx.x;
  const int lane = t & 63;
  const int w = t >> 6;
  const int q = lane >> 4;
  const int m0 = blockIdx.x * BM;  // m fastest: index-panel sharing neighbors
  const int o0 = blockIdx.y * BN;

  lutp[t] = make_float2(c_nf4[t & 15], c_nf4[t >> 4]);

  // B idx staging: thread -> (row=t>>2, 16 ints at (t&3)*16)
  const int brow = t >> 2, bq = t & 3;
  const int* gb = wi + (size_t)(o0 + brow) * K_DIM + bq * 16;
  const float* gs = sc + (size_t)(o0 + brow) * 64;  // 1 scale / row / BK tile
  const int lbo = brow * LDB + bq * 16;             // ushort offset in a buffer

  // A register-direct base: row = m0 + w*32 + mi*16 + (lane&15), 16B at q*8
  const ushort_t* gA = xbf + (size_t)(m0 + w * 32 + (lane & 15)) * K_DIM + q * 8;

  f32x4 acc[2][4];
#pragma unroll
  for (int mi = 0; mi < 2; ++mi)
#pragma unroll
    for (int ni = 0; ni < 4; ++ni) acc[mi][ni] = (f32x4){0.f, 0.f, 0.f, 0.f};

  // ---- prologue: idx tiles 0,1; A tile 0; LUT barrier; dequant tile 0
  int4 bi[2][4];
  float bs[2];
  uint4 a_reg[2][2];
#pragma unroll
  for (int j = 0; j < 4; ++j) bi[0][j] = reinterpret_cast<const int4*>(gb)[j];
  bs[0] = gs[0];
#pragma unroll
  for (int j = 0; j < 4; ++j) bi[1][j] = reinterpret_cast<const int4*>(gb + 64)[j];
  bs[1] = gs[1];
#pragma unroll
  for (int mi = 0; mi < 2; ++mi)
#pragma unroll
    for (int kc = 0; kc < 2; ++kc)
      a_reg[mi][kc] =
          *reinterpret_cast<const uint4*>(gA + (size_t)mi * 16 * K_DIM + kc * 32);

  __syncthreads();  // lutp visible

  {  // dequant tile 0 -> buffer 0
    ushort_t* lb = lds_b + lbo;
    uint4 w0, w1;
    w0.x = dq2(bi[0][0].x, bi[0][0].y, bs[0], lutp);
    w0.y = dq2(bi[0][0].z, bi[0][0].w, bs[0], lutp);
    w0.z = dq2(bi[0][1].x, bi[0][1].y, bs[0], lutp);
    w0.w = dq2(bi[0][1].z, bi[0][1].w, bs[0], lutp);
    w1.x = dq2(bi[0][2].x, bi[0][2].y, bs[0], lutp);
    w1.y = dq2(bi[0][2].z, bi[0][2].w, bs[0], lutp);
    w1.z = dq2(bi[0][3].x, bi[0][3].y, bs[0], lutp);
    w1.w = dq2(bi[0][3].z, bi[0][3].w, bs[0], lutp);
    *reinterpret_cast<uint4*>(lb) = w0;
    *reinterpret_cast<uint4*>(lb + 8) = w1;
  }
#pragma unroll
  for (int j = 0; j < 4; ++j) bi[0][j] = reinterpret_cast<const int4*>(gb + 128)[j];
  bs[0] = gs[2];  // set0 now holds tile 2

  unsigned off_r = 0, off_w = BUF, off_s = 2 * BUF;

#pragma unroll 2
  for (int kt = 0; kt < NT; ++kt) {
    __syncthreads();  // buf[off_r] (tile kt) visible; slot reuse ≥2 apart
    // B fragments for tile kt
    const ushort_t* bb = lds_b + off_r + (lane & 15) * LDB + q * 8;
    bf16x8 bv0[4], bv1[4];
#pragma unroll
    for (int ni = 0; ni < 4; ++ni) bv0[ni] = ldfrag(bb + ni * 16 * LDB);
#pragma unroll
    for (int ni = 0; ni < 4; ++ni) bv1[ni] = ldfrag(bb + ni * 16 * LDB + 32);
    // dequant tile kt+1 -> buf[off_w] (overlaps with MFMA issue below)
    const int ns = (kt + 1) & 1;  // static after unroll-2
    if (kt + 1 < NT) {
      ushort_t* lb = lds_b + off_w + lbo;
      uint4 w0, w1;
      w0.x = dq2(bi[ns][0].x, bi[ns][0].y, bs[ns], lutp);
      w0.y = dq2(bi[ns][0].z, bi[ns][0].w, bs[ns], lutp);
      w0.z = dq2(bi[ns][1].x, bi[ns][1].y, bs[ns], lutp);
      w0.w = dq2(bi[ns][1].z, bi[ns][1].w, bs[ns], lutp);
      w1.x = dq2(bi[ns][2].x, bi[ns][2].y, bs[ns], lutp);
      w1.y = dq2(bi[ns][2].z, bi[ns][2].w, bs[ns], lutp);
      w1.z = dq2(bi[ns][3].x, bi[ns][3].y, bs[ns], lutp);
      w1.w = dq2(bi[ns][3].z, bi[ns][3].w, bs[ns], lutp);
      *reinterpret_cast<uint4*>(lb) = w0;
      *reinterpret_cast<uint4*>(lb + 8) = w1;
    }
    // 16 MFMAs for tile kt (A in registers)
#pragma unroll
    for (int mi = 0; mi < 2; ++mi)
#pragma unroll
      for (int ni = 0; ni < 4; ++ni)
        acc[mi][ni] = __builtin_amdgcn_mfma_f32_16x16x32_bf16(
            asfrag(a_reg[mi][0]), bv0[ni], acc[mi][ni], 0, 0, 0);
#pragma unroll
    for (int mi = 0; mi < 2; ++mi)
#pragma unroll
      for (int ni = 0; ni < 4; ++ni)
        acc[mi][ni] = __builtin_amdgcn_mfma_f32_16x16x32_bf16(
            asfrag(a_reg[mi][1]), bv1[ni], acc[mi][ni], 0, 0, 0);
    // idx prefetch tile kt+3 (depth 2; plain loads stay in flight across barriers)
    if (kt + 3 < NT) {
      const int4* gp = reinterpret_cast<const int4*>(gb + (size_t)(kt + 3) * 64);
#pragma unroll
      for (int j = 0; j < 4; ++j) bi[ns][j] = gp[j];
      bs[ns] = gs[kt + 3];
    }
    // A prefetch tile kt+1
    if (kt + 1 < NT) {
#pragma unroll
      for (int mi = 0; mi < 2; ++mi)
#pragma unroll
        for (int kc = 0; kc < 2; ++kc)
          a_reg[mi][kc] = *reinterpret_cast<const uint4*>(
              gA + (size_t)mi * 16 * K_DIM + (size_t)(kt + 1) * 64 + kc * 32);
    }
    unsigned tmp = off_r;  // rotate triple buffer
    off_r = off_w;
    off_w = off_s;
    off_s = tmp;
  }

  // ---- LoRA K-extension tail: register-direct, no LDS, no barrier
  {
    uint4 la[2], lb4[4];
#pragma unroll
    for (int mi = 0; mi < 2; ++mi)
      la[mi] = *reinterpret_cast<const uint4*>(
          xap + (size_t)(m0 + w * 32 + mi * 16 + (lane & 15)) * 32 + q * 8);
#pragma unroll
    for (int ni = 0; ni < 4; ++ni)
      lb4[ni] = *reinterpret_cast<const uint4*>(
          btp + (size_t)(o0 + ni * 16 + (lane & 15)) * 32 + q * 8);
#pragma unroll
    for (int mi = 0; mi < 2; ++mi)
#pragma unroll
      for (int ni = 0; ni < 4; ++ni)
        acc[mi][ni] = __builtin_amdgcn_mfma_f32_16x16x32_bf16(
            asfrag(la[mi]), asfrag(lb4[ni]), acc[mi][ni], 0, 0, 0);
  }

  // ---- epilogue: plain stores + bias
  const int cl = lane & 15, rg = q * 4;
#pragma unroll
  for (int ni = 0; ni < 4; ++ni) {
    int col = o0 + ni * 16 + cl;
    float bvs = bias[col];
#pragma unroll
    for (int mi = 0; mi < 2; ++mi) {
      int row0 = m0 + w * 32 + mi * 16 + rg;
      float* op = out + (size_t)row0 * N_OUT + col;
#pragma unroll
      for (int i = 0; i < 4; ++i) op[(size_t)i * N_OUT] = acc[mi][ni][i] + bvs;
    }
  }
}

extern "C" void kernel_launch(void* const* d_in, const int* in_sizes, int n_in,
                              void* d_out, int out_size, void* d_ws, size_t ws_size,
                              hipStream_t stream) {
  const float* x = (const float*)d_in[0];
  const int* wi = (const int*)d_in[1];
  const float* sc = (const float*)d_in[2];
  const float* lA = (const float*)d_in[3];
  const float* lB = (const float*)d_in[4];
  const float* bias = (const float*)d_in[5];
  float* out = (float*)d_out;

  char* wsb = (char*)d_ws;
  ushort_t* xbf = (ushort_t*)wsb;                               // 4 MB
  ushort_t* xap = (ushort_t*)(wsb + (4u << 20));                // 32 KB
  ushort_t* btp = (ushort_t*)(wsb + (4u << 20) + (32u << 10));  // 704 KB

  k_prep<<<1579, 256, 0, stream>>>(x, lA, lB, xbf, xap, btp);
  dim3 grid(M_DIM / BM, N_OUT / BN);  // m fastest -> index panel sharing
  k_main<<<grid, 256, 0, stream>>>(xbf, wi, sc, xap, btp, bias, out);
}

// Round 5
// 391.356 us; speedup vs baseline: 1.2225x; 1.0449x over previous
//
#include <hip/hip_runtime.h>
#include <stdint.h>

typedef __bf16 bf16x8 __attribute__((ext_vector_type(8)));
typedef float f32x4 __attribute__((ext_vector_type(4)));
typedef unsigned short ushort_t;

#define N_OUT 11008
#define K_DIM 4096
#define M_DIM 512
#define BM 128
#define BN 64
#define BK 64
#define NT 64            /* K_DIM / BK */
#define LDB 72           /* padded lds_b row, ushorts */
#define BUF (64 * LDB)   /* one B buffer, ushorts (4608) */

__constant__ float c_nf4[16] = {
    -1.0f, -0.6961928009986877f, -0.5250730514526367f, -0.39491748809814453f,
    -0.28444138169288635f, -0.18477343022823334f, -0.09105003625154495f, 0.0f,
    0.07958029955625534f, 0.16093020141124725f, 0.24611230194568634f,
    0.33791524171829224f, 0.44070982933044434f, 0.5626170039176941f,
    0.7229568362236023f, 1.0f};

__device__ __forceinline__ uint32_t pkbf(float lo, float hi) {
  uint32_t ul = __builtin_bit_cast(uint32_t, lo);
  uint32_t uh = __builtin_bit_cast(uint32_t, hi);
  return ((ul + 0x8000u) >> 16) | ((uh + 0x8000u) & 0xffff0000u);
}

__device__ __forceinline__ bf16x8 ldfrag(const ushort_t* p) {
  uint4 r = *reinterpret_cast<const uint4*>(p);
  return __builtin_bit_cast(bf16x8, r);
}

__device__ __forceinline__ bf16x8 asfrag(uint4 r) {
  return __builtin_bit_cast(bf16x8, r);
}

// ---- v_perm-based register dequant -----------------------------------------
// Per tile, build a scale-premultiplied bf16 table split into hi/lo byte
// planes (4 dwords each), then look up 4 nibble-indices per dword via 3-perm
// chains. Math = LUT[i]*s in f32, round-half-up to bf16 (identical to LDS-LUT
// version -> same absmax).
struct DQTab {
  uint32_t thi[4], tlo[4];
};

__device__ __forceinline__ DQTab build_tab(const float* fl, float s) {
  DQTab t;
  uint32_t p[8];
#pragma unroll
  for (int j = 0; j < 8; ++j) p[j] = pkbf(fl[2 * j] * s, fl[2 * j + 1] * s);
#pragma unroll
  for (int j = 0; j < 4; ++j) {
    t.thi[j] = __builtin_amdgcn_perm(p[2 * j + 1], p[2 * j], 0x07050301u);
    t.tlo[j] = __builtin_amdgcn_perm(p[2 * j + 1], p[2 * j], 0x06040200u);
  }
  return t;
}

__device__ __forceinline__ uint32_t pack4(int4 v) {
  return (uint32_t)v.x | ((uint32_t)v.y << 8) | ((uint32_t)v.z << 16) |
         ((uint32_t)v.w << 24);
}

// 4 nibble indices (one per byte of X) -> 2 dwords of packed bf16 weights
__device__ __forceinline__ uint2 lookup4(uint32_t X, const DQTab& t) {
  uint32_t selA = X & 0x07070707u;
  uint32_t m = X & 0x08080808u;
  uint32_t bsel = 0x03020100u + (m >> 1);
  uint32_t hA = __builtin_amdgcn_perm(t.thi[1], t.thi[0], selA);
  uint32_t hB = __builtin_amdgcn_perm(t.thi[3], t.thi[2], selA);
  uint32_t H = __builtin_amdgcn_perm(hB, hA, bsel);
  uint32_t lA = __builtin_amdgcn_perm(t.tlo[1], t.tlo[0], selA);
  uint32_t lB = __builtin_amdgcn_perm(t.tlo[3], t.tlo[2], selA);
  uint32_t L = __builtin_amdgcn_perm(lB, lA, bsel);
  uint2 r;
  r.x = __builtin_amdgcn_perm(H, L, 0x05010400u);
  r.y = __builtin_amdgcn_perm(H, L, 0x07030602u);
  return r;
}

// =============== fused prep: cvt | x@A | B^T ================================
__global__ void k_prep(const float* __restrict__ x, const float* __restrict__ lA,
                       const float* __restrict__ lB, ushort_t* __restrict__ xbf,
                       ushort_t* __restrict__ xap, ushort_t* __restrict__ btp) {
  __shared__ float red[16][17];
  const int b = blockIdx.x, t = threadIdx.x;
  if (b < 1024) {
    int oc = b * 256 + t;
    const float4* s4 = reinterpret_cast<const float4*>(x) + (size_t)oc * 2;
    float4 v0 = s4[0], v1 = s4[1];
    uint4 o;
    o.x = pkbf(v0.x, v0.y);
    o.y = pkbf(v0.z, v0.w);
    o.z = pkbf(v1.x, v1.y);
    o.w = pkbf(v1.z, v1.w);
    ((uint4*)xbf)[oc] = o;
  } else if (b < 1536) {
    int m = b - 1024;
    int r = t & 15, part = t >> 4;
    const float* xr = x + (size_t)m * K_DIM + part * 256;
    const float* ar = lA + (size_t)(part * 256) * 16 + r;
    float acc = 0.f;
#pragma unroll 8
    for (int k = 0; k < 256; ++k) acc += xr[k] * ar[(size_t)k * 16];
    red[part][r] = acc;
    __syncthreads();
    if (t < 32) {
      float v = 0.f;
      if (t < 16) {
        for (int p = 0; p < 16; ++p) v += red[p][t];
        v *= 2.0f;  // SCALING
      }
      uint32_t u = __builtin_bit_cast(uint32_t, v);
      xap[(size_t)m * 32 + t] = (ushort_t)((u + 0x8000u) >> 16);
    }
  } else {
    int o = (b - 1536) * 256 + t;
    uint32_t p[8];
#pragma unroll
    for (int j = 0; j < 8; ++j)
      p[j] = pkbf(lB[(size_t)(2 * j) * N_OUT + o], lB[(size_t)(2 * j + 1) * N_OUT + o]);
    uint4* dst = reinterpret_cast<uint4*>(btp + (size_t)o * 32);
    dst[0] = make_uint4(p[0], p[1], p[2], p[3]);
    dst[1] = make_uint4(p[4], p[5], p[6], p[7]);
    dst[2] = make_uint4(0u, 0u, 0u, 0u);
    dst[3] = make_uint4(0u, 0u, 0u, 0u);
  }
}

// =============== main fused GEMM ============================================
// 1-D grid of 704 blocks, XCD-swizzled: b&7 -> XCD, the 4 m-siblings of each
// o-panel are dispatch-adjacent on the same XCD -> idx panel fetched from HBM
// once, shared via that XCD's L2. BM=128 x BN=64, BK=64, full K.
// A: register-direct global loads (depth 1). B: raw idx int4 regs (depth 2)
// -> v_perm register dequant -> double-buffered LDS, ONE barrier per tile.
__launch_bounds__(256, 3)
__global__ void k_main(const ushort_t* __restrict__ xbf, const int* __restrict__ wi,
                       const float* __restrict__ sc, const ushort_t* __restrict__ xap,
                       const ushort_t* __restrict__ btp, const float* __restrict__ bias,
                       float* __restrict__ out) {
  __shared__ __align__(16) ushort_t lds_b[2 * BUF];  // 18.4 KB

  const int b = blockIdx.x;
  const int xcd = b & 7, sl = b >> 3;
  const int o_idx = xcd * 22 + (sl >> 2);
  if (o_idx >= 172) return;
  const int m0 = (sl & 3) * BM;
  const int o0 = o_idx * BN;

  const int t = threadIdx.x;
  const int lane = t & 63;
  const int w = t >> 6;
  const int q = lane >> 4;

  float fl[16];
#pragma unroll
  for (int i = 0; i < 16; ++i) fl[i] = c_nf4[i];

  // B idx staging: thread -> (row=t>>2, 16 ints at (t&3)*16)
  const int brow = t >> 2, bq = t & 3;
  const int* gb = wi + (size_t)(o0 + brow) * K_DIM + bq * 16;
  const float* gs = sc + (size_t)(o0 + brow) * 64;  // 1 scale / row / BK tile
  const int lbo = brow * LDB + bq * 16;

  // A register-direct base: row = m0 + w*32 + mi*16 + (lane&15), 16B at q*8
  const ushort_t* gA = xbf + (size_t)(m0 + w * 32 + (lane & 15)) * K_DIM + q * 8;

  f32x4 acc[2][4];
#pragma unroll
  for (int mi = 0; mi < 2; ++mi)
#pragma unroll
    for (int ni = 0; ni < 4; ++ni) acc[mi][ni] = (f32x4){0.f, 0.f, 0.f, 0.f};

  // ---- prologue: idx tiles 0(temp),1,2; A tile 0; dequant tile 0 -> buf0
  int4 bi[2][4];
  float bs2[2];
  uint4 a_reg[2][2];
  int4 b0[4];
#pragma unroll
  for (int j = 0; j < 4; ++j) b0[j] = reinterpret_cast<const int4*>(gb)[j];
  float s0 = gs[0];
#pragma unroll
  for (int j = 0; j < 4; ++j) bi[1][j] = reinterpret_cast<const int4*>(gb + 64)[j];
  bs2[1] = gs[1];
#pragma unroll
  for (int j = 0; j < 4; ++j) bi[0][j] = reinterpret_cast<const int4*>(gb + 128)[j];
  bs2[0] = gs[2];
#pragma unroll
  for (int mi = 0; mi < 2; ++mi)
#pragma unroll
    for (int kc = 0; kc < 2; ++kc)
      a_reg[mi][kc] =
          *reinterpret_cast<const uint4*>(gA + (size_t)mi * 16 * K_DIM + kc * 32);

  {  // dequant tile 0 -> buffer 0 (visible to readers via loop-top barrier)
    DQTab tb = build_tab(fl, s0);
    uint2 w0 = lookup4(pack4(b0[0]), tb);
    uint2 w1 = lookup4(pack4(b0[1]), tb);
    uint2 w2 = lookup4(pack4(b0[2]), tb);
    uint2 w3 = lookup4(pack4(b0[3]), tb);
    ushort_t* lb = lds_b + lbo;
    *reinterpret_cast<uint4*>(lb) = make_uint4(w0.x, w0.y, w1.x, w1.y);
    *reinterpret_cast<uint4*>(lb + 8) = make_uint4(w2.x, w2.y, w3.x, w3.y);
  }

#pragma unroll 2
  for (int kt = 0; kt < NT; ++kt) {
    __syncthreads();  // buf[kt&1] (tile kt) visible; double-buffer safe
    const ushort_t* bb = lds_b + (kt & 1) * BUF + (lane & 15) * LDB + q * 8;
    const int ns = (kt + 1) & 1;
    // dequant tile kt+1 -> buf[ns] (VALU only; overlaps frag-read latency)
    if (kt + 1 < NT) {
      DQTab tb = build_tab(fl, bs2[ns]);
      uint2 w0 = lookup4(pack4(bi[ns][0]), tb);
      uint2 w1 = lookup4(pack4(bi[ns][1]), tb);
      uint2 w2 = lookup4(pack4(bi[ns][2]), tb);
      uint2 w3 = lookup4(pack4(bi[ns][3]), tb);
      ushort_t* lb = lds_b + ns * BUF + lbo;
      *reinterpret_cast<uint4*>(lb) = make_uint4(w0.x, w0.y, w1.x, w1.y);
      *reinterpret_cast<uint4*>(lb + 8) = make_uint4(w2.x, w2.y, w3.x, w3.y);
    }
    // first k-half: 8 MFMAs
    {
      bf16x8 bv[4];
#pragma unroll
      for (int ni = 0; ni < 4; ++ni) bv[ni] = ldfrag(bb + ni * 16 * LDB);
#pragma unroll
      for (int mi = 0; mi < 2; ++mi)
#pragma unroll
        for (int ni = 0; ni < 4; ++ni)
          acc[mi][ni] = __builtin_amdgcn_mfma_f32_16x16x32_bf16(
              asfrag(a_reg[mi][0]), bv[ni], acc[mi][ni], 0, 0, 0);
    }
    // second k-half: 8 MFMAs
    {
      bf16x8 bv[4];
#pragma unroll
      for (int ni = 0; ni < 4; ++ni) bv[ni] = ldfrag(bb + ni * 16 * LDB + 32);
#pragma unroll
      for (int mi = 0; mi < 2; ++mi)
#pragma unroll
        for (int ni = 0; ni < 4; ++ni)
          acc[mi][ni] = __builtin_amdgcn_mfma_f32_16x16x32_bf16(
              asfrag(a_reg[mi][1]), bv[ni], acc[mi][ni], 0, 0, 0);
    }
    // idx prefetch tile kt+3 (raw int4, no dependent VALU -> stays in flight)
    if (kt + 3 < NT) {
      const int4* gp = reinterpret_cast<const int4*>(gb + (size_t)(kt + 3) * 64);
#pragma unroll
      for (int j = 0; j < 4; ++j) bi[ns][j] = gp[j];
      bs2[ns] = gs[kt + 3];
    }
    // A prefetch tile kt+1
    if (kt + 1 < NT) {
#pragma unroll
      for (int mi = 0; mi < 2; ++mi)
#pragma unroll
        for (int kc = 0; kc < 2; ++kc)
          a_reg[mi][kc] = *reinterpret_cast<const uint4*>(
              gA + (size_t)mi * 16 * K_DIM + (size_t)(kt + 1) * 64 + kc * 32);
    }
  }

  // ---- LoRA K-extension tail: register-direct
  {
    uint4 la[2], lb4[4];
#pragma unroll
    for (int mi = 0; mi < 2; ++mi)
      la[mi] = *reinterpret_cast<const uint4*>(
          xap + (size_t)(m0 + w * 32 + mi * 16 + (lane & 15)) * 32 + q * 8);
#pragma unroll
    for (int ni = 0; ni < 4; ++ni)
      lb4[ni] = *reinterpret_cast<const uint4*>(
          btp + (size_t)(o0 + ni * 16 + (lane & 15)) * 32 + q * 8);
#pragma unroll
    for (int mi = 0; mi < 2; ++mi)
#pragma unroll
      for (int ni = 0; ni < 4; ++ni)
        acc[mi][ni] = __builtin_amdgcn_mfma_f32_16x16x32_bf16(
            asfrag(la[mi]), asfrag(lb4[ni]), acc[mi][ni], 0, 0, 0);
  }

  // ---- epilogue: plain stores + bias
  const int cl = lane & 15, rg = q * 4;
#pragma unroll
  for (int ni = 0; ni < 4; ++ni) {
    int col = o0 + ni * 16 + cl;
    float bvs = bias[col];
#pragma unroll
    for (int mi = 0; mi < 2; ++mi) {
      int row0 = m0 + w * 32 + mi * 16 + rg;
      float* op = out + (size_t)row0 * N_OUT + col;
#pragma unroll
      for (int i = 0; i < 4; ++i) op[(size_t)i * N_OUT] = acc[mi][ni][i] + bvs;
    }
  }
}

extern "C" void kernel_launch(void* const* d_in, const int* in_sizes, int n_in,
                              void* d_out, int out_size, void* d_ws, size_t ws_size,
                              hipStream_t stream) {
  const float* x = (const float*)d_in[0];
  const int* wi = (const int*)d_in[1];
  const float* sc = (const float*)d_in[2];
  const float* lA = (const float*)d_in[3];
  const float* lB = (const float*)d_in[4];
  const float* bias = (const float*)d_in[5];
  float* out = (float*)d_out;

  char* wsb = (char*)d_ws;
  ushort_t* xbf = (ushort_t*)wsb;                               // 4 MB
  ushort_t* xap = (ushort_t*)(wsb + (4u << 20));                // 32 KB
  ushort_t* btp = (ushort_t*)(wsb + (4u << 20) + (32u << 10));  // 704 KB

  k_prep<<<1579, 256, 0, stream>>>(x, lA, lB, xbf, xap, btp);
  k_main<<<704, 256, 0, stream>>>(xbf, wi, sc, xap, btp, bias, out);
}

// Round 7
// 390.145 us; speedup vs baseline: 1.2263x; 1.0031x over previous
//
#include <hip/hip_runtime.h>
#include <stdint.h>

typedef __bf16 bf16x8 __attribute__((ext_vector_type(8)));
typedef float f32x4 __attribute__((ext_vector_type(4)));
typedef unsigned short ushort_t;

#define N_OUT 11008
#define K_DIM 4096
#define M_DIM 512
#define BM 128
#define BN 64
#define BK 64
#define NT 64            /* K_DIM / BK */
#define LDB 72           /* padded lds W row, ushorts */
#define BUF (64 * LDB)   /* one W buffer, ushorts (4608) */

__constant__ float c_nf4[16] = {
    -1.0f, -0.6961928009986877f, -0.5250730514526367f, -0.39491748809814453f,
    -0.28444138169288635f, -0.18477343022823334f, -0.09105003625154495f, 0.0f,
    0.07958029955625534f, 0.16093020141124725f, 0.24611230194568634f,
    0.33791524171829224f, 0.44070982933044434f, 0.5626170039176941f,
    0.7229568362236023f, 1.0f};

// round-half-up fp32 -> bf16, pack two into u32 (validated absmax=16)
__device__ __forceinline__ uint32_t pkbf(float lo, float hi) {
  uint32_t ul = __builtin_bit_cast(uint32_t, lo);
  uint32_t uh = __builtin_bit_cast(uint32_t, hi);
  return ((ul + 0x8000u) >> 16) | ((uh + 0x8000u) & 0xffff0000u);
}

__device__ __forceinline__ bf16x8 ldfrag(const ushort_t* p) {
  uint4 r = *reinterpret_cast<const uint4*>(p);
  return __builtin_bit_cast(bf16x8, r);
}

__device__ __forceinline__ bf16x8 asfrag(uint4 r) {
  return __builtin_bit_cast(bf16x8, r);
}

// ---- v_perm-based register dequant (validated in r5, absmax 16) ------------
struct DQTab {
  uint32_t thi[4], tlo[4];
};

__device__ __forceinline__ DQTab build_tab(const float* fl, float s) {
  DQTab t;
  uint32_t p[8];
#pragma unroll
  for (int j = 0; j < 8; ++j) p[j] = pkbf(fl[2 * j] * s, fl[2 * j + 1] * s);
#pragma unroll
  for (int j = 0; j < 4; ++j) {
    t.thi[j] = __builtin_amdgcn_perm(p[2 * j + 1], p[2 * j], 0x07050301u);
    t.tlo[j] = __builtin_amdgcn_perm(p[2 * j + 1], p[2 * j], 0x06040200u);
  }
  return t;
}

__device__ __forceinline__ uint32_t pack4(int4 v) {
  return (uint32_t)v.x | ((uint32_t)v.y << 8) | ((uint32_t)v.z << 16) |
         ((uint32_t)v.w << 24);
}

// 4 nibble indices (one per byte of X) -> 2 dwords of packed bf16 weights
__device__ __forceinline__ uint2 lookup4(uint32_t X, const DQTab& t) {
  uint32_t selA = X & 0x07070707u;
  uint32_t m = X & 0x08080808u;
  uint32_t bsel = 0x03020100u + (m >> 1);
  uint32_t hA = __builtin_amdgcn_perm(t.thi[1], t.thi[0], selA);
  uint32_t hB = __builtin_amdgcn_perm(t.thi[3], t.thi[2], selA);
  uint32_t H = __builtin_amdgcn_perm(hB, hA, bsel);
  uint32_t lA = __builtin_amdgcn_perm(t.tlo[1], t.tlo[0], selA);
  uint32_t lB = __builtin_amdgcn_perm(t.tlo[3], t.tlo[2], selA);
  uint32_t L = __builtin_amdgcn_perm(lB, lA, bsel);
  uint2 r;
  r.x = __builtin_amdgcn_perm(H, L, 0x05010400u);
  r.y = __builtin_amdgcn_perm(H, L, 0x07030602u);
  return r;
}

// write one dequanted 16-weight chunk (2 x b128) from 4 packed-nibble dwords
__device__ __forceinline__ void dq_store(const uint32_t* pi, float s,
                                         const float* fl, ushort_t* lb) {
  DQTab tb = build_tab(fl, s);
  uint2 w0 = lookup4(pi[0], tb);
  uint2 w1 = lookup4(pi[1], tb);
  uint2 w2 = lookup4(pi[2], tb);
  uint2 w3 = lookup4(pi[3], tb);
  *reinterpret_cast<uint4*>(lb) = make_uint4(w0.x, w0.y, w1.x, w1.y);
  *reinterpret_cast<uint4*>(lb + 8) = make_uint4(w2.x, w2.y, w3.x, w3.y);
}

// =============== fused prep: cvt | x@A | B^T ================================
__global__ void k_prep(const float* __restrict__ x, const float* __restrict__ lA,
                       const float* __restrict__ lB, ushort_t* __restrict__ xbf,
                       ushort_t* __restrict__ xap, ushort_t* __restrict__ btp) {
  __shared__ float red[16][17];
  const int b = blockIdx.x, t = threadIdx.x;
  if (b < 1024) {
    int oc = b * 256 + t;
    const float4* s4 = reinterpret_cast<const float4*>(x) + (size_t)oc * 2;
    float4 v0 = s4[0], v1 = s4[1];
    uint4 o;
    o.x = pkbf(v0.x, v0.y);
    o.y = pkbf(v0.z, v0.w);
    o.z = pkbf(v1.x, v1.y);
    o.w = pkbf(v1.z, v1.w);
    ((uint4*)xbf)[oc] = o;
  } else if (b < 1536) {
    int m = b - 1024;
    int r = t & 15, part = t >> 4;
    const float* xr = x + (size_t)m * K_DIM + part * 256;
    const float* ar = lA + (size_t)(part * 256) * 16 + r;
    float acc = 0.f;
#pragma unroll 8
    for (int k = 0; k < 256; ++k) acc += xr[k] * ar[(size_t)k * 16];
    red[part][r] = acc;
    __syncthreads();
    if (t < 32) {
      float v = 0.f;
      if (t < 16) {
        for (int p = 0; p < 16; ++p) v += red[p][t];
        v *= 2.0f;  // SCALING
      }
      uint32_t u = __builtin_bit_cast(uint32_t, v);
      xap[(size_t)m * 32 + t] = (ushort_t)((u + 0x8000u) >> 16);
    }
  } else {
    int o = (b - 1536) * 256 + t;
    uint32_t p[8];
#pragma unroll
    for (int j = 0; j < 8; ++j)
      p[j] = pkbf(lB[(size_t)(2 * j) * N_OUT + o], lB[(size_t)(2 * j + 1) * N_OUT + o]);
    uint4* dst = reinterpret_cast<uint4*>(btp + (size_t)o * 32);
    dst[0] = make_uint4(p[0], p[1], p[2], p[3]);
    dst[1] = make_uint4(p[4], p[5], p[6], p[7]);
    dst[2] = make_uint4(0u, 0u, 0u, 0u);
    dst[3] = make_uint4(0u, 0u, 0u, 0u);
  }
}

// =============== main fused GEMM ============================================
// 704 blocks XCD-swizzled. BM=128 x BN=64, BK=64, full K.
// Per stage kt: [barrier] A-prefetch(kt+1) (oldest in vmcnt FIFO) ->
// idx loads(kt+2) -> dequant(kt+1) from 4 packed dwords -> W[ns] ->
// frag reads W[cur] + 16 MFMA (waits only a_reg[cur], issued last stage,
// older than everything recent) -> pack idx(kt+2) into 4 dwords (the ONLY
// late vmcnt wait). LDS = W double-buffer only (18.4 KB).
__launch_bounds__(256, 3)
__global__ void k_main(const ushort_t* __restrict__ xbf, const int* __restrict__ wi,
                       const float* __restrict__ sc, const ushort_t* __restrict__ xap,
                       const ushort_t* __restrict__ btp, const float* __restrict__ bias,
                       float* __restrict__ out) {
  __shared__ __align__(16) ushort_t lds_w[2 * BUF];  // 18.4 KB

  const int b = blockIdx.x;
  const int xcd = b & 7, sl = b >> 3;
  const int o_idx = xcd * 22 + (sl >> 2);
  if (o_idx >= 172) return;
  const int m0 = (sl & 3) * BM;
  const int o0 = o_idx * BN;

  const int t = threadIdx.x;
  const int lane = t & 63;
  const int w = t >> 6;
  const int q = lane >> 4;

  float fl[16];
#pragma unroll
  for (int i = 0; i < 16; ++i) fl[i] = c_nf4[i];

  // idx staging map: thread -> (row=t>>2, 16 idx dwords at (t&3)*16)
  const int brow = t >> 2, bq = t & 3;
  const int* gb = wi + (size_t)(o0 + brow) * K_DIM + bq * 16;
  const float* gs = sc + (size_t)(o0 + brow) * 64;  // 1 scale / row / BK tile
  const int lbo = brow * LDB + bq * 16;

  // A register-direct: row = m0 + w*32 + mi*16 + (lane&15), 16B at q*8
  const ushort_t* gA = xbf + (size_t)(m0 + w * 32 + (lane & 15)) * K_DIM + q * 8;

  f32x4 acc[2][4];
#pragma unroll
  for (int mi = 0; mi < 2; ++mi)
#pragma unroll
    for (int ni = 0; ni < 4; ++ni) acc[mi][ni] = (f32x4){0.f, 0.f, 0.f, 0.f};

  // ---- prologue ----
  uint32_t pi[4];
  {  // tile 0: load, pack, dequant -> W[0]
    uint32_t p0[4];
#pragma unroll
    for (int j = 0; j < 4; ++j) p0[j] = pack4(reinterpret_cast<const int4*>(gb)[j]);
    dq_store(p0, gs[0], fl, lds_w + lbo);
  }
#pragma unroll
  for (int j = 0; j < 4; ++j) pi[j] = pack4(reinterpret_cast<const int4*>(gb + 64)[j]);
  float s_have = gs[1], s_next = gs[2];

  uint4 a_reg[2][2][2];  // [set][mi][kc] explicit ping-pong
#pragma unroll
  for (int mi = 0; mi < 2; ++mi)
#pragma unroll
    for (int kc = 0; kc < 2; ++kc)
      a_reg[0][mi][kc] =
          *reinterpret_cast<const uint4*>(gA + (size_t)mi * 16 * K_DIM + kc * 32);

#pragma unroll 2
  for (int kt = 0; kt < NT; ++kt) {
    __syncthreads();  // W[cur] (tile kt) visible
    const int cur = kt & 1, ns = cur ^ 1;

    // A prefetch tile kt+1 — FIRST, so it is the oldest outstanding load
    if (kt + 1 < NT) {
#pragma unroll
      for (int mi = 0; mi < 2; ++mi)
#pragma unroll
        for (int kc = 0; kc < 2; ++kc)
          a_reg[ns][mi][kc] = *reinterpret_cast<const uint4*>(
              gA + (size_t)mi * 16 * K_DIM + (size_t)(kt + 1) * 64 + kc * 32);
    }
    // idx loads for tile kt+2 (transient regs; waited at pack, end of stage)
    int4 ri[4];
    const bool ld = (kt + 2 < NT);
    if (ld) {
      const int4* gp = reinterpret_cast<const int4*>(gb + (size_t)(kt + 2) * 64);
#pragma unroll
      for (int j = 0; j < 4; ++j) ri[j] = gp[j];
    }
    float snew = (kt + 3 < NT) ? gs[kt + 3] : 0.f;

    // dequant tile kt+1 -> W[ns] (pure VALU on already-resident pi)
    if (kt + 1 < NT) dq_store(pi, s_have, fl, lds_w + ns * BUF + lbo);

    // frag reads + 16 MFMA for tile kt
    const ushort_t* bb = lds_w + cur * BUF + (lane & 15) * LDB + q * 8;
    {
      bf16x8 bv[4];
#pragma unroll
      for (int ni = 0; ni < 4; ++ni) bv[ni] = ldfrag(bb + ni * 16 * LDB);
#pragma unroll
      for (int mi = 0; mi < 2; ++mi)
#pragma unroll
        for (int ni = 0; ni < 4; ++ni)
          acc[mi][ni] = __builtin_amdgcn_mfma_f32_16x16x32_bf16(
              asfrag(a_reg[cur][mi][0]), bv[ni], acc[mi][ni], 0, 0, 0);
    }
    {
      bf16x8 bv[4];
#pragma unroll
      for (int ni = 0; ni < 4; ++ni) bv[ni] = ldfrag(bb + ni * 16 * LDB + 32);
#pragma unroll
      for (int mi = 0; mi < 2; ++mi)
#pragma unroll
        for (int ni = 0; ni < 4; ++ni)
          acc[mi][ni] = __builtin_amdgcn_mfma_f32_16x16x32_bf16(
              asfrag(a_reg[cur][mi][1]), bv[ni], acc[mi][ni], 0, 0, 0);
    }

    // pack idx(kt+2) -> 4 dwords (the late vmcnt wait point)
    if (ld) {
#pragma unroll
      for (int j = 0; j < 4; ++j) pi[j] = pack4(ri[j]);
    }
    s_have = s_next;
    s_next = snew;
  }

  // ---- LoRA K-extension tail: register-direct
  {
    uint4 la[2], lb4[4];
#pragma unroll
    for (int mi = 0; mi < 2; ++mi)
      la[mi] = *reinterpret_cast<const uint4*>(
          xap + (size_t)(m0 + w * 32 + mi * 16 + (lane & 15)) * 32 + q * 8);
#pragma unroll
    for (int ni = 0; ni < 4; ++ni)
      lb4[ni] = *reinterpret_cast<const uint4*>(
          btp + (size_t)(o0 + ni * 16 + (lane & 15)) * 32 + q * 8);
#pragma unroll
    for (int mi = 0; mi < 2; ++mi)
#pragma unroll
      for (int ni = 0; ni < 4; ++ni)
        acc[mi][ni] = __builtin_amdgcn_mfma_f32_16x16x32_bf16(
            asfrag(la[mi]), asfrag(lb4[ni]), acc[mi][ni], 0, 0, 0);
  }

  // ---- epilogue: plain stores + bias
  const int cl = lane & 15, rg = q * 4;
#pragma unroll
  for (int ni = 0; ni < 4; ++ni) {
    int col = o0 + ni * 16 + cl;
    float bvs = bias[col];
#pragma unroll
    for (int mi = 0; mi < 2; ++mi) {
      int row0 = m0 + w * 32 + mi * 16 + rg;
      float* op = out + (size_t)row0 * N_OUT + col;
#pragma unroll
      for (int i = 0; i < 4; ++i) op[(size_t)i * N_OUT] = acc[mi][ni][i] + bvs;
    }
  }
}

extern "C" void kernel_launch(void* const* d_in, const int* in_sizes, int n_in,
                              void* d_out, int out_size, void* d_ws, size_t ws_size,
                              hipStream_t stream) {
  const float* x = (const float*)d_in[0];
  const int* wi = (const int*)d_in[1];
  const float* sc = (const float*)d_in[2];
  const float* lA = (const float*)d_in[3];
  const float* lB = (const float*)d_in[4];
  const float* bias = (const float*)d_in[5];
  float* out = (float*)d_out;

  char* wsb = (char*)d_ws;
  ushort_t* xbf = (ushort_t*)wsb;                               // 4 MB
  ushort_t* xap = (ushort_t*)(wsb + (4u << 20));                // 32 KB
  ushort_t* btp = (ushort_t*)(wsb + (4u << 20) + (32u << 10));  // 704 KB

  k_prep<<<1579, 256, 0, stream>>>(x, lA, lB, xbf, xap, btp);
  k_main<<<704, 256, 0, stream>>>(xbf, wi, sc, xap, btp, bias, out);
}